// Round 7
// baseline (646.787 us; speedup 1.0000x reference)
//
#include <hip/hip_runtime.h>
#include <math.h>

#define NB 8            // batch
#define JJ 421          // J = 5*81 + 16
#define HDCN 256        // HDC
#define PP (JJ*HDCN)    // 107776 pixels per (batch,channel) plane
#define STEPS 20

typedef __attribute__((ext_vector_type(8))) short bf16x8;
typedef __attribute__((ext_vector_type(4))) float f32x4;
typedef __attribute__((ext_vector_type(2))) float f32x2;
typedef __attribute__((ext_vector_type(4))) unsigned int uint4v;
typedef __attribute__((ext_vector_type(2))) int int2v;
typedef unsigned short ushort;
typedef unsigned int uint;

// ---- bf16 helpers: RNE round, packed hi/lo state (x ~ hi + lo) ----
__device__ __forceinline__ ushort f2bf(float f) {
    union { float f; uint u; } a; a.f = f;
    uint r = 0x7fffu + ((a.u >> 16) & 1u);     // round-to-nearest-even
    return (ushort)((a.u + r) >> 16);
}
__device__ __forceinline__ uint splitpack(float x) {
    uint u = __float_as_uint(x);
    uint r = 0x7fffu + ((u >> 16) & 1u);
    uint hib = (u + r) & 0xffff0000u;          // RNE bf16 hi (float bits)
    float lo = x - __uint_as_float(hib);       // exact residual
    return hib | f2bf(lo);                     // [hi bf16 | lo bf16]
}
__device__ __forceinline__ float unpack2(uint p) {
    return __uint_as_float(p & 0xffff0000u) + __uint_as_float(p << 16);
}
__device__ __forceinline__ float tanh_fast(float x) {
    float e = __expf(2.f * x);
    return 1.f - 2.f / (e + 1.f);              // inf-safe
}
__device__ __forceinline__ float wave_reduce_sum(float v) {
#pragma unroll
    for (int off = 32; off > 0; off >>= 1) v += __shfl_down(v, off);
    return v;
}
// cross-half (+/-32 lanes) sum on the VALU pipe (falls back to shfl)
__device__ __forceinline__ float red32(float d) {
#if __has_builtin(__builtin_amdgcn_permlane32_swap)
    int2v pr = __builtin_amdgcn_permlane32_swap(__float_as_int(d), __float_as_int(d), false, false);
    return __int_as_float(pr.x) + __int_as_float(pr.y);
#else
    return d + __shfl_xor(d, 32);
#endif
}

// ---------------------------------------------------------------------------
// k_wprep: A-operand planes, 3-plane K-repack (bf16 RNE, K=32 per plane):
//   plane p = dd; k-groups of 8: [hi tau 0-7 | hi tau 8-14 | lo tau 0-7 |
//   lo tau 8-14]  (tau = c*3+dj; w value independent of hi/lo group)
//   Pw[p][oc][k] = w1[oc, tau=k&15, dd=p]  (tau 15 -> 0 pad)
//   w2p[oc][8] = {w2[0..4][oc], b1[oc], 0, 0}
// ---------------------------------------------------------------------------
__global__ __launch_bounds__(256) void k_wprep(
    const float* __restrict__ w1, const float* __restrict__ b1,
    const float* __restrict__ w2,
    ushort* __restrict__ Pw, float* __restrict__ w2p)
{
    int t = threadIdx.x;
    for (int idx = t; idx < 3072; idx += 256) {
        int p = idx >> 10, rem = idx & 1023, oc = rem >> 5, k = rem & 31;
        int tau = k & 15;
        float v = 0.f;
        if (tau < 15) v = w1[oc * 45 + (tau / 3) * 9 + (tau % 3) * 3 + p];
        Pw[idx] = f2bf(v);
    }
    int oc = t >> 3, o = t & 7;
    float v = 0.f;
    if (o < 5) v = w2[o * 32 + oc];
    else if (o == 5) v = b1[oc];
    w2p[t] = v;
}

// ---------------------------------------------------------------------------
// k_prep: s[b] = sum_i data[b,i], data = concat(data_input, structure, pe)
// ---------------------------------------------------------------------------
__global__ __launch_bounds__(128) void k_prep(
    const float* __restrict__ din, const float* __restrict__ stin,
    const float* __restrict__ m_in, const float* __restrict__ m_out,
    float* __restrict__ sbuf)
{
    int b = blockIdx.x, t = threadIdx.x;
    float acc = 0.f;
    for (int k = t; k < 324; k += 128) acc += din[b * 324 + k];
    for (int k = t; k < 81;  k += 128) acc += stin[b * 81 + k];
    if (t < 16) {
        int i = t;
        float pos_in  = m_in[b]  * 0.01f;
        float pos_out = m_out[b] * 0.01f;
        float div = powf(10000.0f, (float)(2 * (i / 2)) / 16.0f);
        float ai = pos_in / div, ao = pos_out / div;
        float v = ((i & 1) == 0) ? 0.5f * (sinf(ai) + cosf(ai))
                                 : 0.5f * (cosf(ai) + sinf(ao));
        acc += v;
    }
    __shared__ float part[2];
    float w = wave_reduce_sum(acc);
    if ((t & 63) == 0) part[t >> 6] = w;
    __syncthreads();
    if (t == 0) sbuf[b] = part[0] + part[1];
}

// ---------------------------------------------------------------------------
// k_x0: x0[b,o,jd] = tanh( A - 2p*B + p^2*C + cb[o] ), stored packed hi/lo
// ---------------------------------------------------------------------------
__global__ __launch_bounds__(128) void k_x0(
    const float* __restrict__ rbf, const float* __restrict__ hdc,
    const float* __restrict__ cw, const float* __restrict__ cb,
    const float* __restrict__ sbuf, uint* __restrict__ x0)
{
    __shared__ float wl[320];
    __shared__ float Cw[5];
    __shared__ float sb[8];
    __shared__ float cbs[5];
    int t = threadIdx.x;
    for (int k = t; k < 320; k += 128) wl[k] = cw[k];
    if (t < 8)   sb[t] = sbuf[t];
    if (t < 5)   cbs[t] = cb[t];
    __syncthreads();
    if (t < 5) { float c = 0.f; for (int r = 0; r < 64; ++r) c += wl[t * 64 + r]; Cw[t] = c; }
    __syncthreads();

    int jd = blockIdx.x * 128 + t;       // 842*128 == PP exactly
    float A[5]  = {0, 0, 0, 0, 0};
    float Bv[5] = {0, 0, 0, 0, 0};
    for (int r = 0; r < 64; ++r) {
        float v  = rbf[(size_t)r * PP + jd];
        float v2 = v * v;
#pragma unroll
        for (int o = 0; o < 5; ++o) {
            float w = wl[o * 64 + r];
            A[o]  = fmaf(w, v2, A[o]);
            Bv[o] = fmaf(w, v,  Bv[o]);
        }
    }
#pragma unroll
    for (int b = 0; b < 8; ++b) {
        float p  = sb[b] * hdc[(size_t)b * PP + jd];
        float p2 = p * p;
#pragma unroll
        for (int o = 0; o < 5; ++o) {
            float val = A[o] - 2.f * p * Bv[o] + p2 * Cw[o] + cbs[o];
            x0[(size_t)(b * 5 + o) * PP + jd] = splitpack(tanh_fast(val));
        }
    }
}

// ---------------------------------------------------------------------------
// k_nca: one NCA step. ONE WAVE per block; block owns (b, j-pair, 64-px
//   d-slice). Wave-private LDS Bs (66 rows: 64 own px + 2 halo px), built
//   and consumed by the same wave -> NO BARRIERS (in-order DS pipe gives
//   same-wave RAW ordering). Waves run phase-decoupled for latency hiding.
//   GEMM per row: M=32 oc, K=96 (3 planes), N=64 px (4 nt-tiles).
//   Epilogue: after gq-reduce every lane holds full dx for col nt*16+m;
//   lane's own pixel is the nt==gq slice -> direct coalesced store.
// ---------------------------------------------------------------------------
__global__ __launch_bounds__(64, 4) void k_nca(
    const uint* __restrict__ xin, uint* __restrict__ xout,
    const ushort* __restrict__ Pw, const float* __restrict__ w2p,
    const float* __restrict__ b2)
{
    __shared__ __align__(16) uint Bs[2][66 * 16];   // 8448 B, wave-private

    const int lane = threadIdx.x;
    const int bid = blockIdx.x;
    const int b = bid & 7;               // XCD affinity: batch per XCD
    const int rem = bid >> 3;
    const int ws_ = rem & 3;             // d-slice 0..3
    const int pj = rem >> 2;             // 0..210
    const int j0 = pj * 2;
    const bool has1 = (j0 + 1) < JJ;
    const int P = ws_ << 6;              // slice base pixel
    const int m = lane & 15, gq = lane >> 4;

    // ---- A fragments (6x b128 global, L2-hot) ----
    bf16x8 Ap[3][2];
#pragma unroll
    for (int p = 0; p < 3; ++p)
#pragma unroll
        for (int mt = 0; mt < 2; ++mt)
            Ap[p][mt] = *(const bf16x8*)(Pw + p * 1024 + (mt * 16 + m) * 32 + gq * 8);

    float b2r[5];
#pragma unroll
    for (int o = 0; o < 5; ++o) b2r[o] = b2[o];

    const uint* xb = xin + (size_t)b * 5 * PP;

    // ---- stage own pixel (coalesced 64-wide), pack rows lane+1 ----
    uint v[5][4];
#pragma unroll
    for (int c = 0; c < 5; ++c)
#pragma unroll
        for (int rr = 0; rr < 4; ++rr) {
            int jj = j0 - 1 + rr;
            uint val = 0;
            if (jj >= 0 && jj < JJ) val = xb[(size_t)(c * JJ + jj) * HDCN + P + lane];
            v[c][rr] = val;
        }

#pragma unroll
    for (int r = 0; r < 2; ++r) {
        if (r == 1 && !has1) break;
        uint xh[8], xl[8];
#pragma unroll
        for (int w = 0; w < 8; ++w) {
            int k0 = 2 * w, k1 = 2 * w + 1;
            uint a = (k0 < 15) ? v[k0 / 3][k0 % 3 + r] : 0u;
            uint c = (k1 < 15) ? v[k1 / 3][k1 % 3 + r] : 0u;
            xh[w] = (a >> 16) | (c & 0xffff0000u);
            xl[w] = (a & 0xffffu) | (c << 16);
        }
        int rho = lane + 1;
        int s = (rho >> 1) & 3;
        uint* rb = &Bs[r][rho * 16];
        *(uint4v*)(rb + ((0 ^ s) << 2)) = (uint4v){xh[0], xh[1], xh[2], xh[3]};
        *(uint4v*)(rb + ((1 ^ s) << 2)) = (uint4v){xh[4], xh[5], xh[6], xh[7]};
        *(uint4v*)(rb + ((2 ^ s) << 2)) = (uint4v){xl[0], xl[1], xl[2], xl[3]};
        *(uint4v*)(rb + ((3 ^ s) << 2)) = (uint4v){xl[4], xl[5], xl[6], xl[7]};
    }

    // ---- halo pixels P-1 (row 0) and P+64 (row 65), lanes 0 / 63 ----
    if (lane == 0 || lane == 63) {
        int qh = (lane == 0) ? P - 1 : P + 64;
        int rho = (lane == 0) ? 0 : 65;
        bool qok = (qh >= 0) && (qh < HDCN);
        uint vh[5][4];
#pragma unroll
        for (int c = 0; c < 5; ++c)
#pragma unroll
            for (int rr = 0; rr < 4; ++rr) {
                int jj = j0 - 1 + rr;
                uint val = 0;
                if (qok && jj >= 0 && jj < JJ) val = xb[(size_t)(c * JJ + jj) * HDCN + qh];
                vh[c][rr] = val;
            }
#pragma unroll
        for (int r = 0; r < 2; ++r) {
            if (r == 1 && !has1) break;
            uint xh[8], xl[8];
#pragma unroll
            for (int w = 0; w < 8; ++w) {
                int k0 = 2 * w, k1 = 2 * w + 1;
                uint a = (k0 < 15) ? vh[k0 / 3][k0 % 3 + r] : 0u;
                uint c = (k1 < 15) ? vh[k1 / 3][k1 % 3 + r] : 0u;
                xh[w] = (a >> 16) | (c & 0xffff0000u);
                xl[w] = (a & 0xffffu) | (c << 16);
            }
            int s = (rho >> 1) & 3;
            uint* rb = &Bs[r][rho * 16];
            *(uint4v*)(rb + ((0 ^ s) << 2)) = (uint4v){xh[0], xh[1], xh[2], xh[3]};
            *(uint4v*)(rb + ((1 ^ s) << 2)) = (uint4v){xh[4], xh[5], xh[6], xh[7]};
            *(uint4v*)(rb + ((2 ^ s) << 2)) = (uint4v){xl[0], xl[1], xl[2], xl[3]};
            *(uint4v*)(rb + ((3 ^ s) << 2)) = (uint4v){xl[4], xl[5], xl[6], xl[7]};
        }
    }
    // no __syncthreads: single wave, DS pipe is in-order per wave

    // ---- per output row: 24 MFMAs + epilogue ----
#pragma unroll
    for (int r = 0; r < 2; ++r) {
        if (r == 1 && !has1) break;
        const int j = j0 + r;

        f32x4 acc[2][4];
#pragma unroll
        for (int mt = 0; mt < 2; ++mt)
#pragma unroll
            for (int nt = 0; nt < 4; ++nt) acc[mt][nt] = (f32x4){0.f, 0.f, 0.f, 0.f};

#pragma unroll
        for (int nt = 0; nt < 4; ++nt) {
#pragma unroll
            for (int p = 0; p < 3; ++p) {
                int rho = nt * 16 + m + p;
                int s2 = (rho >> 1) & 3;
                bf16x8 Bf = *(const bf16x8*)(&Bs[r][rho * 16] + ((gq ^ s2) << 2));
                acc[0][nt] = __builtin_amdgcn_mfma_f32_16x16x32_bf16(Ap[p][0], Bf, acc[0][nt], 0, 0, 0);
                acc[1][nt] = __builtin_amdgcn_mfma_f32_16x16x32_bf16(Ap[p][1], Bf, acc[1][nt], 0, 0, 0);
            }
        }

        // w2/b1 loaded per row (volatile: keeps live range out of MFMA phase)
        float w2r[2][4][5], b1r[2][4];
#pragma unroll
        for (int mt = 0; mt < 2; ++mt)
#pragma unroll
            for (int i = 0; i < 4; ++i) {
                int oc = mt * 16 + gq * 4 + i;
                f32x4 a = *(volatile const f32x4*)(w2p + oc * 8);
                f32x2 e = *(volatile const f32x2*)(w2p + oc * 8 + 4);
                w2r[mt][i][0] = a[0]; w2r[mt][i][1] = a[1];
                w2r[mt][i][2] = a[2]; w2r[mt][i][3] = a[3];
                w2r[mt][i][4] = e[0]; b1r[mt][i] = e[1];
            }

        float dxs[5] = {0, 0, 0, 0, 0};
#pragma unroll
        for (int nt = 0; nt < 4; ++nt) {
            float dx[5] = {0, 0, 0, 0, 0};
#pragma unroll
            for (int mt = 0; mt < 2; ++mt)
#pragma unroll
                for (int i = 0; i < 4; ++i) {
                    float h = fmaxf(acc[mt][nt][i] + b1r[mt][i], 0.f);
#pragma unroll
                    for (int o = 0; o < 5; ++o) dx[o] = fmaf(w2r[mt][i][o], h, dx[o]);
                }
#pragma unroll
            for (int o = 0; o < 5; ++o) {
                dx[o] += __shfl_xor(dx[o], 16);
                dx[o] = red32(dx[o]);
                if (nt == gq) dxs[o] = dx[o];   // lane's own pixel slice
            }
        }

        // coalesced store: residual from staged v, all from registers
        const size_t base_bj = (size_t)b * 5 * PP + (size_t)j * HDCN + P + lane;
#pragma unroll
        for (int c = 0; c < 5; ++c) {
            float xn = unpack2(v[c][r + 1]) + dxs[c] + b2r[c];
            xout[base_bj + (size_t)c * PP] = splitpack(xn);
        }
    }
}

// ---------------------------------------------------------------------------
// k_mean: m[bc,j] = mean_d tanh(x[bc,j,d]); 8 j-rows per block, 32 thr/row
// ---------------------------------------------------------------------------
__global__ __launch_bounds__(256) void k_mean(
    const uint* __restrict__ x, float* __restrict__ m)
{
    int bc = blockIdx.x / 53, jblk = blockIdx.x % 53;
    int t = threadIdx.x;
    int jr = jblk * 8 + (t >> 5);
    if (jr >= JJ) return;
    const uint* p = x + (size_t)bc * PP + (size_t)jr * HDCN + (t & 31) * 8;
    uint4v u0 = *(const uint4v*)p;
    uint4v u1 = *(const uint4v*)(p + 4);
    float s = 0.f;
#pragma unroll
    for (int k = 0; k < 4; ++k) s += tanh_fast(unpack2(u0[k]));
#pragma unroll
    for (int k = 0; k < 4; ++k) s += tanh_fast(unpack2(u1[k]));
#pragma unroll
    for (int off = 16; off > 0; off >>= 1) s += __shfl_down(s, off, 32);
    if ((t & 31) == 0) m[bc * JJ + jr] = s * (1.0f / 256.0f);
}

// ---------------------------------------------------------------------------
// k_out: adaptive pool J=421 -> 81, outputs concat(r,g,b,a,s)
// ---------------------------------------------------------------------------
__global__ __launch_bounds__(256) void k_out(
    const float* __restrict__ m, float* __restrict__ out)
{
    int idx = blockIdx.x * 256 + threadIdx.x;
    if (idx >= 5 * NB * 81) return;
    int c = idx / (NB * 81);
    int rem = idx % (NB * 81);
    int b = rem / 81;
    int o = rem % 81;
    int s_ = (o * JJ) / 81;
    int e_ = ((o + 1) * JJ + 80) / 81;
    float acc = 0.f;
    for (int jj = s_; jj < e_; ++jj) acc += m[(b * 5 + c) * JJ + jj];
    out[idx] = acc / (float)(e_ - s_);
}

// ---------------------------------------------------------------------------
extern "C" void kernel_launch(void* const* d_in, const int* in_sizes, int n_in,
                              void* d_out, int out_size, void* d_ws, size_t ws_size,
                              hipStream_t stream) {
    const float* data_in  = (const float*)d_in[0];
    const float* struc_in = (const float*)d_in[1];
    const float* meta_in  = (const float*)d_in[2];
    const float* meta_out = (const float*)d_in[3];
    const float* rbf      = (const float*)d_in[4];
    const float* hdc      = (const float*)d_in[5];
    const float* cw       = (const float*)d_in[6];
    const float* cb       = (const float*)d_in[7];
    const float* w1       = (const float*)d_in[8];
    const float* b1       = (const float*)d_in[9];
    const float* w2       = (const float*)d_in[10];
    const float* b2       = (const float*)d_in[11];
    float* out = (float*)d_out;

    float* ws   = (float*)d_ws;
    float* sbuf = ws;                          // 8 floats
    float* mbuf = ws + 64;                     // 40*421 floats
    ushort* Pw  = (ushort*)(ws + 20480);       // 3072 ushorts (3 planes)
    float* w2p  = ws + 22528;                  // 256 floats
    uint* xA = (uint*)(ws + 32768);            // [8,5,421,256] packed hi/lo
    uint* xB = xA + (size_t)NB * 5 * PP;

    k_wprep<<<1, 256, 0, stream>>>(w1, b1, w2, Pw, w2p);
    k_prep<<<NB, 128, 0, stream>>>(data_in, struc_in, meta_in, meta_out, sbuf);
    k_x0<<<842, 128, 0, stream>>>(rbf, hdc, cw, cb, sbuf, xA);

    for (int step = 0; step < STEPS; ++step) {
        const uint* xi = (step & 1) ? xB : xA;
        uint*       xo = (step & 1) ? xA : xB;
        k_nca<<<NB * 211 * 4, 64, 0, stream>>>(xi, xo, Pw, w2p, b2);
    }
    k_mean<<<(40 * 53), 256, 0, stream>>>(xA, mbuf);
    k_out<<<(5 * NB * 81 + 255) / 256, 256, 0, stream>>>(mbuf, out);
}

// Round 8
// 402.993 us; speedup vs baseline: 1.6050x; 1.6050x over previous
//
#include <hip/hip_runtime.h>
#include <math.h>

#define NB 8            // batch
#define JJ 421          // J = 5*81 + 16
#define HDCN 256        // HDC
#define PP (JJ*HDCN)    // 107776 pixels per (batch,channel) plane
#define STEPS 20

typedef __attribute__((ext_vector_type(8))) short bf16x8;
typedef __attribute__((ext_vector_type(4))) float f32x4;
typedef __attribute__((ext_vector_type(2))) float f32x2;
typedef __attribute__((ext_vector_type(4))) unsigned int uint4v;
typedef __attribute__((ext_vector_type(2))) int int2v;
typedef unsigned short ushort;
typedef unsigned int uint;

// ---- bf16 helpers: RNE round, packed hi/lo state (x ~ hi + lo) ----
__device__ __forceinline__ ushort f2bf(float f) {
    union { float f; uint u; } a; a.f = f;
    uint r = 0x7fffu + ((a.u >> 16) & 1u);     // round-to-nearest-even
    return (ushort)((a.u + r) >> 16);
}
__device__ __forceinline__ uint splitpack(float x) {
    uint u = __float_as_uint(x);
    uint r = 0x7fffu + ((u >> 16) & 1u);
    uint hib = (u + r) & 0xffff0000u;          // RNE bf16 hi (float bits)
    float lo = x - __uint_as_float(hib);       // exact residual
    return hib | f2bf(lo);                     // [hi bf16 | lo bf16]
}
__device__ __forceinline__ float unpack2(uint p) {
    return __uint_as_float(p & 0xffff0000u) + __uint_as_float(p << 16);
}
__device__ __forceinline__ float tanh_fast(float x) {
    float e = __expf(2.f * x);
    return 1.f - 2.f / (e + 1.f);              // inf-safe
}
__device__ __forceinline__ float wave_reduce_sum(float v) {
#pragma unroll
    for (int off = 32; off > 0; off >>= 1) v += __shfl_down(v, off);
    return v;
}
// cross-half (+/-32 lanes) sum on the VALU pipe (falls back to shfl)
__device__ __forceinline__ float red32(float d) {
#if __has_builtin(__builtin_amdgcn_permlane32_swap)
    int2v pr = __builtin_amdgcn_permlane32_swap(__float_as_int(d), __float_as_int(d), false, false);
    return __int_as_float(pr.x) + __int_as_float(pr.y);
#else
    return d + __shfl_xor(d, 32);
#endif
}

// ---------------------------------------------------------------------------
// k_wprep: A-operand planes, 3-plane K-repack (bf16 RNE, K=32 per plane):
//   plane p = dd; k-groups of 8: [hi tau 0-7 | hi tau 8-14 | lo tau 0-7 |
//   lo tau 8-14]  (tau = c*3+dj; w value independent of hi/lo group)
//   Pw[p][oc][k] = w1[oc, tau=k&15, dd=p]  (tau 15 -> 0 pad)
//   w2p[oc][8] = {w2[0..4][oc], b1[oc], 0, 0}
// ---------------------------------------------------------------------------
__global__ __launch_bounds__(256) void k_wprep(
    const float* __restrict__ w1, const float* __restrict__ b1,
    const float* __restrict__ w2,
    ushort* __restrict__ Pw, float* __restrict__ w2p)
{
    int t = threadIdx.x;
    for (int idx = t; idx < 3072; idx += 256) {
        int p = idx >> 10, rem = idx & 1023, oc = rem >> 5, k = rem & 31;
        int tau = k & 15;
        float v = 0.f;
        if (tau < 15) v = w1[oc * 45 + (tau / 3) * 9 + (tau % 3) * 3 + p];
        Pw[idx] = f2bf(v);
    }
    int oc = t >> 3, o = t & 7;
    float v = 0.f;
    if (o < 5) v = w2[o * 32 + oc];
    else if (o == 5) v = b1[oc];
    w2p[t] = v;
}

// ---------------------------------------------------------------------------
// k_prep: s[b] = sum_i data[b,i], data = concat(data_input, structure, pe)
// ---------------------------------------------------------------------------
__global__ __launch_bounds__(128) void k_prep(
    const float* __restrict__ din, const float* __restrict__ stin,
    const float* __restrict__ m_in, const float* __restrict__ m_out,
    float* __restrict__ sbuf)
{
    int b = blockIdx.x, t = threadIdx.x;
    float acc = 0.f;
    for (int k = t; k < 324; k += 128) acc += din[b * 324 + k];
    for (int k = t; k < 81;  k += 128) acc += stin[b * 81 + k];
    if (t < 16) {
        int i = t;
        float pos_in  = m_in[b]  * 0.01f;
        float pos_out = m_out[b] * 0.01f;
        float div = powf(10000.0f, (float)(2 * (i / 2)) / 16.0f);
        float ai = pos_in / div, ao = pos_out / div;
        float v = ((i & 1) == 0) ? 0.5f * (sinf(ai) + cosf(ai))
                                 : 0.5f * (cosf(ai) + sinf(ao));
        acc += v;
    }
    __shared__ float part[2];
    float w = wave_reduce_sum(acc);
    if ((t & 63) == 0) part[t >> 6] = w;
    __syncthreads();
    if (t == 0) sbuf[b] = part[0] + part[1];
}

// ---------------------------------------------------------------------------
// k_x0: x0[b,o,jd] = tanh( A - 2p*B + p^2*C + cb[o] ), stored packed hi/lo
// ---------------------------------------------------------------------------
__global__ __launch_bounds__(128) void k_x0(
    const float* __restrict__ rbf, const float* __restrict__ hdc,
    const float* __restrict__ cw, const float* __restrict__ cb,
    const float* __restrict__ sbuf, uint* __restrict__ x0)
{
    __shared__ float wl[320];
    __shared__ float Cw[5];
    __shared__ float sb[8];
    __shared__ float cbs[5];
    int t = threadIdx.x;
    for (int k = t; k < 320; k += 128) wl[k] = cw[k];
    if (t < 8)   sb[t] = sbuf[t];
    if (t < 5)   cbs[t] = cb[t];
    __syncthreads();
    if (t < 5) { float c = 0.f; for (int r = 0; r < 64; ++r) c += wl[t * 64 + r]; Cw[t] = c; }
    __syncthreads();

    int jd = blockIdx.x * 128 + t;       // 842*128 == PP exactly
    float A[5]  = {0, 0, 0, 0, 0};
    float Bv[5] = {0, 0, 0, 0, 0};
    for (int r = 0; r < 64; ++r) {
        float v  = rbf[(size_t)r * PP + jd];
        float v2 = v * v;
#pragma unroll
        for (int o = 0; o < 5; ++o) {
            float w = wl[o * 64 + r];
            A[o]  = fmaf(w, v2, A[o]);
            Bv[o] = fmaf(w, v,  Bv[o]);
        }
    }
#pragma unroll
    for (int b = 0; b < 8; ++b) {
        float p  = sb[b] * hdc[(size_t)b * PP + jd];
        float p2 = p * p;
#pragma unroll
        for (int o = 0; o < 5; ++o) {
            float val = A[o] - 2.f * p * Bv[o] + p2 * Cw[o] + cbs[o];
            x0[(size_t)(b * 5 + o) * PP + jd] = splitpack(tanh_fast(val));
        }
    }
}

// ---------------------------------------------------------------------------
// k_nca: one NCA step, TWO consecutive j-rows per block (grid 8*211=1688).
//   GEMM per row: M=32 oc, K=96 (3 planes of K=32), N=256 px.
//   Plane p = dd; k-groups = [xh 0-7 | xh 8-14 | xl 0-7 | xl 8-14] ->
//   B-frag chunk index = gq, row = px + p. 3 ds_read_b128 + 6 MFMAs per nt.
//   Bs row layout (64B): [xh(2 chunks) | xl(2 chunks)], chunks XOR-swizzled
//   by ((row>>1)&3); rows 0 and 257 are zero pads (d=-1,256).
//   Epilogue: fp32 fma-chain W2 + shuffle reduce; after the reduce, every
//   lane holds the full dx of column nt*16+m, and for nt==gq that column is
//   the lane's own staged pixel (px = t) -> register-only coalesced store,
//   residual from the staged v (no Ds bounce, no xin re-read).
//   dofinal: last step accumulates m[bc][j] = mean_d tanh(x_new) in-block
//   (fuses k_mean) and skips the dead final-state store.
// ---------------------------------------------------------------------------
__global__ __launch_bounds__(256, 3) void k_nca(
    const uint* __restrict__ xin, uint* __restrict__ xout,
    const ushort* __restrict__ Pw, const float* __restrict__ w2p,
    const float* __restrict__ b2, float* __restrict__ mbuf, int dofinal)
{
    __shared__ uint Bs[2][258 * 16];     // 33 KB
    __shared__ float Ms[2][5][4];        // mean partials (last step only)

    const int t = threadIdx.x;
    const int b = blockIdx.x & 7;        // XCD affinity: batch per XCD
    const int pj = blockIdx.x >> 3;      // 0..210
    const int j0 = pj * 2;
    const bool has1 = (j0 + 1) < JJ;     // pj=210 -> lone row 420
    const int lane = t & 63, wv = t >> 6;
    const int m = lane & 15, gq = lane >> 4;

    // ---- A fragments (6x b128 global, L2-hot) ----
    bf16x8 Ap[3][2];
#pragma unroll
    for (int p = 0; p < 3; ++p)
#pragma unroll
        for (int mt = 0; mt < 2; ++mt)
            Ap[p][mt] = *(const bf16x8*)(Pw + p * 1024 + (mt * 16 + m) * 32 + gq * 8);

    // ---- w2/b1/b2 ----
    float w2r[2][4][5], b1r[2][4], b2r[5];
#pragma unroll
    for (int mt = 0; mt < 2; ++mt)
#pragma unroll
        for (int i = 0; i < 4; ++i) {
            int oc = mt * 16 + gq * 4 + i;
            const float* wp = w2p + oc * 8;
            f32x4 a = *(const f32x4*)wp;
            f32x2 e = *(const f32x2*)(wp + 4);
            w2r[mt][i][0] = a[0]; w2r[mt][i][1] = a[1];
            w2r[mt][i][2] = a[2]; w2r[mt][i][3] = a[3];
            w2r[mt][i][4] = e[0]; b1r[mt][i] = e[1];
        }
#pragma unroll
    for (int o = 0; o < 5; ++o) b2r[o] = b2[o];

    // ---- stage 4 input rows x 5 ch, build both Bs ----
    uint v[5][4];
    {
        const uint* xb = xin + (size_t)b * 5 * PP;
#pragma unroll
        for (int c = 0; c < 5; ++c)
#pragma unroll
            for (int rr = 0; rr < 4; ++rr) {
                int jj = j0 - 1 + rr;
                uint val = 0;
                if (jj >= 0 && jj < JJ) val = xb[(size_t)(c * JJ + jj) * HDCN + t];
                v[c][rr] = val;
            }
        const int row = t + 1;
        const int s = (row >> 1) & 3;
#pragma unroll
        for (int r = 0; r < 2; ++r) {
            if (r == 1 && !has1) break;
            uint xh[8], xl[8];
#pragma unroll
            for (int w = 0; w < 8; ++w) {
                int k0 = 2 * w, k1 = 2 * w + 1;
                uint a = (k0 < 15) ? v[k0 / 3][k0 % 3 + r] : 0u;
                uint c = (k1 < 15) ? v[k1 / 3][k1 % 3 + r] : 0u;
                xh[w] = (a >> 16) | (c & 0xffff0000u);
                xl[w] = (a & 0xffffu) | (c << 16);
            }
            uint* rb = &Bs[r][row * 16];
            *(uint4v*)(rb + ((0 ^ s) << 2)) = (uint4v){xh[0], xh[1], xh[2], xh[3]};
            *(uint4v*)(rb + ((1 ^ s) << 2)) = (uint4v){xh[4], xh[5], xh[6], xh[7]};
            *(uint4v*)(rb + ((2 ^ s) << 2)) = (uint4v){xl[0], xl[1], xl[2], xl[3]};
            *(uint4v*)(rb + ((3 ^ s) << 2)) = (uint4v){xl[4], xl[5], xl[6], xl[7]};
        }
        if (t < 4) {
            uint* zr = &Bs[t >> 1][(t & 1) ? 257 * 16 : 0];
            uint4v z = (uint4v){0, 0, 0, 0};
            ((uint4v*)zr)[0] = z; ((uint4v*)zr)[1] = z;
            ((uint4v*)zr)[2] = z; ((uint4v*)zr)[3] = z;
        }
    }
    __syncthreads();

    // ---- per output row: 24 MFMAs + epilogue ----
#pragma unroll
    for (int r = 0; r < 2; ++r) {
        if (r == 1 && !has1) break;
        const int j = j0 + r;

        f32x4 acc[2][4];
#pragma unroll
        for (int mt = 0; mt < 2; ++mt)
#pragma unroll
            for (int nt = 0; nt < 4; ++nt) acc[mt][nt] = (f32x4){0.f, 0.f, 0.f, 0.f};

#pragma unroll
        for (int nt = 0; nt < 4; ++nt) {
            int px = (wv << 6) + (nt << 4) + m;
#pragma unroll
            for (int p = 0; p < 3; ++p) {
                int row = px + p;
                int s2 = (row >> 1) & 3;
                bf16x8 Bf = *(const bf16x8*)(&Bs[r][row * 16] + ((gq ^ s2) << 2));
                acc[0][nt] = __builtin_amdgcn_mfma_f32_16x16x32_bf16(Ap[p][0], Bf, acc[0][nt], 0, 0, 0);
                acc[1][nt] = __builtin_amdgcn_mfma_f32_16x16x32_bf16(Ap[p][1], Bf, acc[1][nt], 0, 0, 0);
            }
        }

        // W2 projection (fp32 fma chain) + cross-lane reduce (keep nt==gq)
        float dxs[5] = {0, 0, 0, 0, 0};
#pragma unroll
        for (int nt = 0; nt < 4; ++nt) {
            float dx[5] = {0, 0, 0, 0, 0};
#pragma unroll
            for (int mt = 0; mt < 2; ++mt)
#pragma unroll
                for (int i = 0; i < 4; ++i) {
                    float h = fmaxf(acc[mt][nt][i] + b1r[mt][i], 0.f);
#pragma unroll
                    for (int o = 0; o < 5; ++o) dx[o] = fmaf(w2r[mt][i][o], h, dx[o]);
                }
#pragma unroll
            for (int o = 0; o < 5; ++o) {
                dx[o] += __shfl_xor(dx[o], 16);
                dx[o] = red32(dx[o]);
                if (nt == gq) dxs[o] = dx[o];   // lane's own pixel (px == t)
            }
        }

        // coalesced store from registers: residual from staged v
        const size_t base_bj = (size_t)b * 5 * PP + (size_t)j * HDCN;
        float xnv[5];
#pragma unroll
        for (int c = 0; c < 5; ++c) {
            xnv[c] = unpack2(v[c][r + 1]) + dxs[c] + b2r[c];
            if (!dofinal) xout[base_bj + (size_t)c * PP + t] = splitpack(xnv[c]);
        }

        // fused mean (last step only): wave partials of sum_d tanh(x_new)
        if (dofinal) {
#pragma unroll
            for (int c = 0; c < 5; ++c) {
                float s = wave_reduce_sum(tanh_fast(xnv[c]));
                if (lane == 0) Ms[r][c][wv] = s;
            }
        }
    }

    if (dofinal) {
        __syncthreads();
        if (t < 10) {
            int rr = t / 5, c = t % 5;
            if (rr == 0 || has1) {
                float s = Ms[rr][c][0] + Ms[rr][c][1] + Ms[rr][c][2] + Ms[rr][c][3];
                mbuf[(b * 5 + c) * JJ + (j0 + rr)] = s * (1.0f / 256.0f);
            }
        }
    }
}

// ---------------------------------------------------------------------------
// k_out: adaptive pool J=421 -> 81, outputs concat(r,g,b,a,s)
// ---------------------------------------------------------------------------
__global__ __launch_bounds__(256) void k_out(
    const float* __restrict__ m, float* __restrict__ out)
{
    int idx = blockIdx.x * 256 + threadIdx.x;
    if (idx >= 5 * NB * 81) return;
    int c = idx / (NB * 81);
    int rem = idx % (NB * 81);
    int b = rem / 81;
    int o = rem % 81;
    int s_ = (o * JJ) / 81;
    int e_ = ((o + 1) * JJ + 80) / 81;
    float acc = 0.f;
    for (int jj = s_; jj < e_; ++jj) acc += m[(b * 5 + c) * JJ + jj];
    out[idx] = acc / (float)(e_ - s_);
}

// ---------------------------------------------------------------------------
extern "C" void kernel_launch(void* const* d_in, const int* in_sizes, int n_in,
                              void* d_out, int out_size, void* d_ws, size_t ws_size,
                              hipStream_t stream) {
    const float* data_in  = (const float*)d_in[0];
    const float* struc_in = (const float*)d_in[1];
    const float* meta_in  = (const float*)d_in[2];
    const float* meta_out = (const float*)d_in[3];
    const float* rbf      = (const float*)d_in[4];
    const float* hdc      = (const float*)d_in[5];
    const float* cw       = (const float*)d_in[6];
    const float* cb       = (const float*)d_in[7];
    const float* w1       = (const float*)d_in[8];
    const float* b1       = (const float*)d_in[9];
    const float* w2       = (const float*)d_in[10];
    const float* b2       = (const float*)d_in[11];
    float* out = (float*)d_out;

    float* ws   = (float*)d_ws;
    float* sbuf = ws;                          // 8 floats
    float* mbuf = ws + 64;                     // 40*421 floats
    ushort* Pw  = (ushort*)(ws + 20480);       // 3072 ushorts (3 planes)
    float* w2p  = ws + 22528;                  // 256 floats
    uint* xA = (uint*)(ws + 32768);            // [8,5,421,256] packed hi/lo
    uint* xB = xA + (size_t)NB * 5 * PP;

    k_wprep<<<1, 256, 0, stream>>>(w1, b1, w2, Pw, w2p);
    k_prep<<<NB, 128, 0, stream>>>(data_in, struc_in, meta_in, meta_out, sbuf);
    k_x0<<<842, 128, 0, stream>>>(rbf, hdc, cw, cb, sbuf, xA);

    for (int step = 0; step < STEPS; ++step) {
        const uint* xi = (step & 1) ? xB : xA;
        uint*       xo = (step & 1) ? xA : xB;
        k_nca<<<NB * 211, 256, 0, stream>>>(xi, xo, Pw, w2p, b2, mbuf,
                                            (step == STEPS - 1) ? 1 : 0);
    }
    k_out<<<(5 * NB * 81 + 255) / 256, 256, 0, stream>>>(mbuf, out);
}